// Round 12
// baseline (274.876 us; speedup 1.0000x reference)
//
#include <hip/hip_runtime.h>
#include <hip/hip_cooperative_groups.h>
namespace cg = cooperative_groups;

// GCNConv forward on MI355X — R12: single cooperative persistent kernel.
//   phase0: cursor init
//   phaseA: scatter tiles (bucket radix, coalesced runs) + gemm tiles
//           (g = bf16(x@W)) on one persistent grid
//   phaseB: per-bucket counting sort -> u16 CSR + rsdeg + dinv
//   phaseC: pull — wave per node, uint4 gathers, fma with dinv[src],
//           shfl reduce, single f32 out write
// N=65536, E=1048576, D=64.  Bucket = dst>>7 (512 buckets), arena cap 4096.

#define N_DIM 64
#define NBUCK 512
#define NODEB 128
#define CUR_STRIDE 16
#define TILE 4096
#define SCAT_NB 256       // E / TILE
#define GEMM_NB 1024      // N / 64
#define SCAP 2560

__global__ void __launch_bounds__(512, 4) k_all(
        const float* __restrict__ x, const float* __restrict__ W,
        const int* __restrict__ src, const int* __restrict__ dst,
        unsigned* __restrict__ cursor, unsigned* __restrict__ packed,
        unsigned short* __restrict__ g2s, unsigned short* __restrict__ csr2,
        uint2* __restrict__ rsdeg, float* __restrict__ dinv,
        const float4* __restrict__ bias4, float4* __restrict__ out4,
        int E, int N) {
    cg::grid_group grid = cg::this_grid();
    __shared__ __align__(16) unsigned sh[10752];   // 43 KB union
    int tid = threadIdx.x;

    // ---- phase 0: init bucket cursors ----
    if (blockIdx.x == 0) cursor[tid * CUR_STRIDE] = 0u;
    grid.sync();

    // ---- phase A: scatter tiles [0,SCAT_NB) + gemm tiles [SCAT_NB,...) ----
    for (int t = blockIdx.x; t < SCAT_NB + GEMM_NB; t += gridDim.x) {
        if (t < SCAT_NB) {
            unsigned* tile   = sh;            // 4096
            unsigned* stile  = sh + 4096;     // 4096
            unsigned* cnt    = sh + 8192;     // 512
            unsigned* scn    = sh + 8704;     // 512
            unsigned* base_l = sh + 9216;     // 512
            unsigned* curw   = sh + 9728;     // 512
            unsigned* gbase  = sh + 10240;    // 512
            int e0 = t * TILE;
            int cntT = E - e0; if (cntT > TILE) cntT = TILE;

            if (cntT == TILE) {
                const int4* d4 = (const int4*)(dst + e0);
                const int4* s4 = (const int4*)(src + e0);
                uint4* t4 = (uint4*)tile;
                for (int i = tid; i < TILE / 4; i += 512) {
                    int4 d = d4[i]; int4 s = s4[i];
                    t4[i] = make_uint4(((unsigned)d.x << 16) | (unsigned)s.x,
                                       ((unsigned)d.y << 16) | (unsigned)s.y,
                                       ((unsigned)d.z << 16) | (unsigned)s.z,
                                       ((unsigned)d.w << 16) | (unsigned)s.w);
                }
            } else {
                for (int i = tid; i < cntT; i += 512)
                    tile[i] = ((unsigned)dst[e0 + i] << 16) | (unsigned)src[e0 + i];
            }
            cnt[tid] = 0u;
            __syncthreads();

            for (int i = tid; i < cntT; i += 512) atomicAdd(&cnt[tile[i] >> 23], 1u);
            __syncthreads();
            scn[tid] = cnt[tid];
            __syncthreads();
            for (int off = 1; off < NBUCK; off <<= 1) {
                unsigned u = (tid >= off) ? scn[tid - off] : 0u;
                __syncthreads();
                scn[tid] += u;
                __syncthreads();
            }
            {
                unsigned ex = scn[tid] - cnt[tid];
                base_l[tid] = ex;
                curw[tid]   = ex;
                unsigned c  = cnt[tid];
                gbase[tid]  = ((unsigned)tid << 12) +
                              (c ? atomicAdd(&cursor[tid * CUR_STRIDE], c) : 0u);
            }
            __syncthreads();

            for (int i = tid; i < cntT; i += 512) {
                unsigned p = tile[i];
                unsigned r = atomicAdd(&curw[p >> 23], 1u);
                stile[r] = p;
            }
            __syncthreads();

            for (int i = tid; i < cntT; i += 512) {
                unsigned p = stile[i];
                unsigned bin = p >> 23;
                packed[gbase[bin] + ((unsigned)i - base_l[bin])] = p;
            }
        } else {
            float* sX  = (float*)sh;            // 4096 words
            float* sWt = (float*)(sh + 4096);   // 4160 words
            int gb = t - SCAT_NB;
            for (int idx = tid; idx < 64 * 64; idx += 512) {
                int k = idx >> 6, c = idx & 63;
                sWt[c * 65 + k] = W[k * 64 + c];
            }
            const float4* x4p = (const float4*)(x + (size_t)gb * 64 * 64);
            float4* sX4 = (float4*)sX;
            sX4[tid]       = x4p[tid];
            sX4[tid + 512] = x4p[tid + 512];
            __syncthreads();

            int c  = tid & 63;
            int rg = tid >> 6;
            int row0 = gb * 64 + rg * 8;
            float acc[8];
#pragma unroll
            for (int r = 0; r < 8; ++r) acc[r] = 0.f;
            for (int k = 0; k < 64; k += 4) {
                float4 w4 = *(const float4*)&sWt[c * 65 + k];
#pragma unroll
                for (int r = 0; r < 8; ++r) {
                    float4 x4 = *(const float4*)&sX[(rg * 8 + r) * 64 + k];
                    acc[r] = fmaf(x4.x, w4.x, acc[r]);
                    acc[r] = fmaf(x4.y, w4.y, acc[r]);
                    acc[r] = fmaf(x4.z, w4.z, acc[r]);
                    acc[r] = fmaf(x4.w, w4.w, acc[r]);
                }
            }
#pragma unroll
            for (int r = 0; r < 8; ++r) {
                int row = row0 + r;
                unsigned bu = __float_as_uint(acc[r]);
                bu += 0x7FFFu + ((bu >> 16) & 1u);            // RNE to bf16
                g2s[(size_t)row * 64 + c] = (unsigned short)(bu >> 16);
            }
        }
        __syncthreads();   // protect sh reuse across persistent iterations
    }
    grid.sync();

    // ---- phase B: per-bucket counting sort ----
    for (int b = blockIdx.x; b < NBUCK; b += gridDim.x) {
        unsigned* tile = sh;                                  // 2560
        unsigned short* stile = (unsigned short*)(sh + 2560); // 1280 words
        unsigned* cnt  = sh + 3840;
        unsigned* scn  = sh + 3968;
        unsigned* curw = sh + 4096;
        unsigned base  = (unsigned)b << 12;
        unsigned total = cursor[b * CUR_STRIDE];
        if (total > SCAP) total = SCAP;

        for (unsigned i = tid; i < total; i += 512) tile[i] = packed[base + i];
        if (tid < NODEB) cnt[tid] = 0u;
        __syncthreads();

        for (unsigned i = tid; i < total; i += 512)
            atomicAdd(&cnt[(tile[i] >> 16) & 127u], 1u);
        __syncthreads();
        if (tid < NODEB) scn[tid] = cnt[tid];
        __syncthreads();
        for (int off = 1; off < NODEB; off <<= 1) {
            unsigned u = 0;
            if (tid < NODEB && tid >= off) u = scn[tid - off];
            __syncthreads();
            if (tid < NODEB) scn[tid] += u;
            __syncthreads();
        }
        if (tid < NODEB) {
            unsigned ex = scn[tid] - cnt[tid];
            curw[tid] = ex;
            rsdeg[b * NODEB + tid] = make_uint2(base + ex, cnt[tid]);
            dinv[b * NODEB + tid]  = rsqrtf((float)(cnt[tid] + 1u));
        }
        __syncthreads();

        for (unsigned i = tid; i < total; i += 512) {
            unsigned p = tile[i];
            unsigned r = atomicAdd(&curw[(p >> 16) & 127u], 1u);
            stile[r] = (unsigned short)(p & 0xFFFFu);
        }
        __syncthreads();

        unsigned* csr2_32  = (unsigned*)csr2;
        unsigned* stile_32 = (unsigned*)stile;
        unsigned n2 = (total + 1u) >> 1;
        for (unsigned i = tid; i < n2; i += 512)
            csr2_32[(base >> 1) + i] = stile_32[i];
        __syncthreads();
    }
    grid.sync();

    // ---- phase C: pull (8 waves = 8 nodes per block-iteration) ----
    const uint4* tbl4 = (const uint4*)g2s;
    int lane = tid & 63;
    int slot = lane >> 3;
    int ch8  = lane & 7;
    for (int grp = blockIdx.x; grp < (N >> 3); grp += gridDim.x) {
        int node = grp * 8 + (tid >> 6);
        uint2 rd = rsdeg[node];
        unsigned k  = rd.x;
        unsigned k1 = rd.x + rd.y;
        float a0 = 0.f, a1 = 0.f, a2 = 0.f, a3 = 0.f;
        float a4 = 0.f, a5 = 0.f, a6 = 0.f, a7 = 0.f;
#define ACC(u, d) do { \
        a0 = fmaf(__uint_as_float((u).x << 16), (d), a0); \
        a1 = fmaf(__uint_as_float((u).x & 0xFFFF0000u), (d), a1); \
        a2 = fmaf(__uint_as_float((u).y << 16), (d), a2); \
        a3 = fmaf(__uint_as_float((u).y & 0xFFFF0000u), (d), a3); \
        a4 = fmaf(__uint_as_float((u).z << 16), (d), a4); \
        a5 = fmaf(__uint_as_float((u).z & 0xFFFF0000u), (d), a5); \
        a6 = fmaf(__uint_as_float((u).w << 16), (d), a6); \
        a7 = fmaf(__uint_as_float((u).w & 0xFFFF0000u), (d), a7); } while (0)
        for (; k + 16 <= k1; k += 16) {
            unsigned i0 = csr2[k + slot];
            unsigned i1 = csr2[k + 8 + slot];
            float d0 = dinv[i0], d1 = dinv[i1];
            uint4 u = tbl4[(size_t)i0 * 8 + ch8];
            uint4 v = tbl4[(size_t)i1 * 8 + ch8];
            ACC(u, d0); ACC(v, d1);
        }
        if (k + 8 <= k1) {
            unsigned i0 = csr2[k + slot];
            float d0 = dinv[i0];
            uint4 u = tbl4[(size_t)i0 * 8 + ch8];
            ACC(u, d0);
            k += 8;
        }
        if (k < k1) {
            unsigned rem = k1 - k;
            if ((unsigned)slot < rem) {
                unsigned i0 = csr2[k + slot];
                float d0 = dinv[i0];
                uint4 u = tbl4[(size_t)i0 * 8 + ch8];
                ACC(u, d0);
            }
        }
        a0 += __shfl_xor(a0, 8); a0 += __shfl_xor(a0, 16); a0 += __shfl_xor(a0, 32);
        a1 += __shfl_xor(a1, 8); a1 += __shfl_xor(a1, 16); a1 += __shfl_xor(a1, 32);
        a2 += __shfl_xor(a2, 8); a2 += __shfl_xor(a2, 16); a2 += __shfl_xor(a2, 32);
        a3 += __shfl_xor(a3, 8); a3 += __shfl_xor(a3, 16); a3 += __shfl_xor(a3, 32);
        a4 += __shfl_xor(a4, 8); a4 += __shfl_xor(a4, 16); a4 += __shfl_xor(a4, 32);
        a5 += __shfl_xor(a5, 8); a5 += __shfl_xor(a5, 16); a5 += __shfl_xor(a5, 32);
        a6 += __shfl_xor(a6, 8); a6 += __shfl_xor(a6, 16); a6 += __shfl_xor(a6, 32);
        a7 += __shfl_xor(a7, 8); a7 += __shfl_xor(a7, 16); a7 += __shfl_xor(a7, 32);
        if (lane < 8) {
            float dv = dinv[node];
            uint4 s = tbl4[(size_t)node * 8 + ch8];      // self-loop term
            ACC(s, dv);
            float4 b0 = bias4[ch8 * 2], b1 = bias4[ch8 * 2 + 1];
            float4 r0, r1;
            r0.x = a0 * dv + b0.x; r0.y = a1 * dv + b0.y;
            r0.z = a2 * dv + b0.z; r0.w = a3 * dv + b0.w;
            r1.x = a4 * dv + b1.x; r1.y = a5 * dv + b1.y;
            r1.z = a6 * dv + b1.z; r1.w = a7 * dv + b1.w;
            out4[(size_t)node * 16 + ch8 * 2]     = r0;
            out4[(size_t)node * 16 + ch8 * 2 + 1] = r1;
        }
#undef ACC
    }
}

extern "C" void kernel_launch(void* const* d_in, const int* in_sizes, int n_in,
                              void* d_out, int out_size, void* d_ws, size_t ws_size,
                              hipStream_t stream) {
    const float* x  = (const float*)d_in[0];
    const int*   ei = (const int*)d_in[1];
    const float* W  = (const float*)d_in[2];
    const float* b  = (const float*)d_in[3];

    int N = in_sizes[0] / N_DIM;   // 65536
    int E = in_sizes[1] / 2;       // 1048576
    const int* src = ei;
    const int* dst = ei + E;

    // Workspace layout (bytes):
    //   cursor  u32[512*16]     @ 0          (32 KB)
    //   dinv    f32[N]          @ 32768      (256 KB)
    //   rsdeg   uint2[N]        @ 294912     (512 KB)
    //   packed  u32[512*4096]   @ 819200     (8 MB arena)
    //   csr2    u16[512*4096]   @ 9207808    (4 MB arena)
    //   g bf16  u16[N*64]       @ 13402112   (8 MB)
    char* ws = (char*)d_ws;
    unsigned*       cursor = (unsigned*)(ws);
    float*          dinv   = (float*)   (ws + 32768);
    uint2*          rsdeg  = (uint2*)   (ws + 294912);
    unsigned*       packed = (unsigned*)(ws + 819200);
    unsigned short* csr2   = (unsigned short*)(ws + 9207808);
    unsigned short* g2s    = (unsigned short*)(ws + 13402112);
    const float4*   bias4  = (const float4*)b;
    float4*         out4   = (float4*)d_out;

    int blocksPerCU = 0;
    hipOccupancyMaxActiveBlocksPerMultiprocessor(&blocksPerCU, k_all, 512, 0);
    if (blocksPerCU < 1) blocksPerCU = 1;
    int grid = blocksPerCU * 256;
    if (grid > 2048) grid = 2048;

    void* args[] = { (void*)&x, (void*)&W, (void*)&src, (void*)&dst,
                     (void*)&cursor, (void*)&packed, (void*)&g2s, (void*)&csr2,
                     (void*)&rsdeg, (void*)&dinv, (void*)&bias4, (void*)&out4,
                     (void*)&E, (void*)&N };
    hipLaunchCooperativeKernel((const void*)k_all, dim3(grid), dim3(512),
                               args, 0, stream);
}

// Round 13
// 136.483 us; speedup vs baseline: 2.0140x; 2.0140x over previous
//
#include <hip/hip_runtime.h>

// GCNConv forward on MI355X — R13 = R11 revert (best: 138.5 us).
// R12's cooperative single-kernel regressed 2x: the 43 KB LDS union + VGPR
// cap throttled the pull phase's occupancy. Separate launches let each phase
// run at its own optimal occupancy; dependency chain (scatter+gemm) ->
// sort/dinv -> pull is structurally minimal (pull needs complete dinv/g).
// N=65536, E=1048576, D=64.  Bucket = dst>>7 (512 buckets), arena cap 4096.

#define N_DIM 64
#define NBUCK 512         // buckets (dst>>7), 128 nodes each
#define NODEB 128         // nodes per bucket
#define CUR_STRIDE 16     // one 64B line per bucket cursor
#define TILE 4096         // edges per scatter block
#define SCAT_NB 256       // scatter blocks (E / TILE)
#define SCAP 2560         // sort LDS capacity (bucket load ~2048 +- ~45)

__global__ void k_init(unsigned* __restrict__ cursor) {
    cursor[threadIdx.x * CUR_STRIDE] = 0u;   // 512 threads, 1 block
}

// Fused kernel: blocks [0,SCAT_NB) bucket-scatter the edge list;
// blocks [SCAT_NB, SCAT_NB+N/64) compute g = bf16(x @ W) (64 rows each).
__global__ void __launch_bounds__(512) k_fused(
        const float* __restrict__ x, const float* __restrict__ W,
        const int* __restrict__ src, const int* __restrict__ dst,
        unsigned* __restrict__ cursor, unsigned* __restrict__ packed,
        unsigned short* __restrict__ g2s, int E) {
    __shared__ __align__(16) unsigned sh[10752];
    int tid = threadIdx.x;

    if (blockIdx.x < SCAT_NB) {
        // ---- scatter path: stage -> count -> scan -> local sort -> runs ----
        unsigned* tile   = sh;            // 4096
        unsigned* stile  = sh + 4096;     // 4096
        unsigned* cnt    = sh + 8192;     // 512
        unsigned* scn    = sh + 8704;     // 512
        unsigned* base_l = sh + 9216;     // 512
        unsigned* curw   = sh + 9728;     // 512
        unsigned* gbase  = sh + 10240;    // 512
        int e0 = blockIdx.x * TILE;
        int cntT = E - e0; if (cntT > TILE) cntT = TILE;

        if (cntT == TILE) {
            const int4* d4 = (const int4*)(dst + e0);
            const int4* s4 = (const int4*)(src + e0);
            uint4* t4 = (uint4*)tile;
            for (int i = tid; i < TILE / 4; i += 512) {
                int4 d = d4[i]; int4 s = s4[i];
                t4[i] = make_uint4(((unsigned)d.x << 16) | (unsigned)s.x,
                                   ((unsigned)d.y << 16) | (unsigned)s.y,
                                   ((unsigned)d.z << 16) | (unsigned)s.z,
                                   ((unsigned)d.w << 16) | (unsigned)s.w);
            }
        } else {
            for (int i = tid; i < cntT; i += 512)
                tile[i] = ((unsigned)dst[e0 + i] << 16) | (unsigned)src[e0 + i];
        }
        cnt[tid] = 0u;
        __syncthreads();

        for (int i = tid; i < cntT; i += 512) atomicAdd(&cnt[tile[i] >> 23], 1u);
        __syncthreads();
        scn[tid] = cnt[tid];
        __syncthreads();
        for (int off = 1; off < NBUCK; off <<= 1) {
            unsigned u = (tid >= off) ? scn[tid - off] : 0u;
            __syncthreads();
            scn[tid] += u;
            __syncthreads();
        }
        {
            unsigned ex = scn[tid] - cnt[tid];
            base_l[tid] = ex;
            curw[tid]   = ex;
            unsigned c  = cnt[tid];
            gbase[tid]  = ((unsigned)tid << 12) +
                          (c ? atomicAdd(&cursor[tid * CUR_STRIDE], c) : 0u);
        }
        __syncthreads();

        for (int i = tid; i < cntT; i += 512) {
            unsigned p = tile[i];
            unsigned r = atomicAdd(&curw[p >> 23], 1u);
            stile[r] = p;
        }
        __syncthreads();

        for (int i = tid; i < cntT; i += 512) {
            unsigned p = stile[i];
            unsigned bin = p >> 23;
            packed[gbase[bin] + ((unsigned)i - base_l[bin])] = p;   // coalesced runs
        }
    } else {
        // ---- gemm path: g = bf16(x @ W), 64 rows per block, 8 waves ----
        float* sX  = (float*)sh;            // 64x64 = 4096 words
        float* sWt = (float*)(sh + 4096);   // 64x65 = 4160 words
        int gb = blockIdx.x - SCAT_NB;
        for (int idx = tid; idx < 64 * 64; idx += 512) {
            int k = idx >> 6, c = idx & 63;
            sWt[c * 65 + k] = W[k * 64 + c];
        }
        const float4* x4p = (const float4*)(x + (size_t)gb * 64 * 64);
        float4* sX4 = (float4*)sX;
        sX4[tid]       = x4p[tid];
        sX4[tid + 512] = x4p[tid + 512];
        __syncthreads();

        int c  = tid & 63;
        int rg = tid >> 6;                  // wave 0..7 owns rows rg*8..rg*8+7
        int row0 = gb * 64 + rg * 8;
        float acc[8];
#pragma unroll
        for (int r = 0; r < 8; ++r) acc[r] = 0.f;
        for (int k = 0; k < 64; k += 4) {
            float4 w4 = *(const float4*)&sWt[c * 65 + k];
#pragma unroll
            for (int r = 0; r < 8; ++r) {
                float4 x4 = *(const float4*)&sX[(rg * 8 + r) * 64 + k];
                acc[r] = fmaf(x4.x, w4.x, acc[r]);
                acc[r] = fmaf(x4.y, w4.y, acc[r]);
                acc[r] = fmaf(x4.z, w4.z, acc[r]);
                acc[r] = fmaf(x4.w, w4.w, acc[r]);
            }
        }
#pragma unroll
        for (int r = 0; r < 8; ++r) {
            int row = row0 + r;
            unsigned bu = __float_as_uint(acc[r]);
            bu += 0x7FFFu + ((bu >> 16) & 1u);            // RNE to bf16
            g2s[(size_t)row * 64 + c] = (unsigned short)(bu >> 16);
        }
    }
}

// One block per bucket: stage run in LDS, counting-sort by node-in-bucket
// (128 bins), write csr2 back as coalesced u32 pairs; emit rsdeg + dinv.
__global__ void __launch_bounds__(512) k_sort(
        const unsigned* __restrict__ packed, const unsigned* __restrict__ cursor,
        unsigned short* __restrict__ csr2, uint2* __restrict__ rsdeg,
        float* __restrict__ dinv) {
    __shared__ unsigned tile[SCAP];          // 10 KB
    __shared__ unsigned short stile[SCAP];   // 5 KB
    __shared__ unsigned cnt[NODEB], scn[NODEB], curw[NODEB];
    int b = blockIdx.x, t = threadIdx.x;
    unsigned base  = (unsigned)b << 12;
    unsigned total = cursor[b * CUR_STRIDE];
    if (total > SCAP) total = SCAP;          // statistically unreachable guard

    for (unsigned i = t; i < total; i += 512) tile[i] = packed[base + i];
    if (t < NODEB) cnt[t] = 0u;
    __syncthreads();

    for (unsigned i = t; i < total; i += 512)
        atomicAdd(&cnt[(tile[i] >> 16) & 127u], 1u);
    __syncthreads();
    if (t < NODEB) scn[t] = cnt[t];
    __syncthreads();
    for (int off = 1; off < NODEB; off <<= 1) {
        unsigned u = 0;
        if (t < NODEB && t >= off) u = scn[t - off];
        __syncthreads();
        if (t < NODEB) scn[t] += u;
        __syncthreads();
    }
    if (t < NODEB) {
        unsigned ex = scn[t] - cnt[t];
        curw[t] = ex;
        rsdeg[b * NODEB + t] = make_uint2(base + ex, cnt[t]);
        dinv[b * NODEB + t]  = rsqrtf((float)(cnt[t] + 1u));   // +1 self-loop
    }
    __syncthreads();

    for (unsigned i = t; i < total; i += 512) {
        unsigned p = tile[i];
        unsigned r = atomicAdd(&curw[(p >> 16) & 127u], 1u);
        stile[r] = (unsigned short)(p & 0xFFFFu);
    }
    __syncthreads();

    unsigned* csr2_32  = (unsigned*)csr2;
    unsigned* stile_32 = (unsigned*)stile;
    unsigned n2 = (total + 1u) >> 1;         // base is even; pad slot unread
    for (unsigned i = t; i < n2; i += 512)
        csr2_32[(base >> 1) + i] = stile_32[i];
}

// One wave per node. lane = (slot in [0,8), ch8 in [0,8)); each slot gathers
// one uint4 (8 bf16 ch) + dinv[src] per edge, 2-deep -> 16 edges in flight.
// acc += h_src * dinv_src (fma); shfl_xor(8,16,32) reduce; lanes 0..7 write
// 2 float4 (256 B/node contiguous). out = (sum + h_i*dinv_i)*dinv_i + b.
__global__ void __launch_bounds__(256) k_pull(
        const uint4* __restrict__ tbl4, const uint2* __restrict__ rsdeg,
        const unsigned short* __restrict__ csr2, const float* __restrict__ dinv,
        const float4* __restrict__ bias4, float4* __restrict__ out4, int n) {
    int node = blockIdx.x * 4 + (threadIdx.x >> 6);
    if (node >= n) return;
    int lane = threadIdx.x & 63;
    int slot = lane >> 3;
    int ch8  = lane & 7;
    uint2 rd = rsdeg[node];
    unsigned k  = rd.x;
    unsigned k1 = rd.x + rd.y;
    float a0 = 0.f, a1 = 0.f, a2 = 0.f, a3 = 0.f;
    float a4 = 0.f, a5 = 0.f, a6 = 0.f, a7 = 0.f;
#define ACC(u, d) do { \
        a0 = fmaf(__uint_as_float((u).x << 16), (d), a0); \
        a1 = fmaf(__uint_as_float((u).x & 0xFFFF0000u), (d), a1); \
        a2 = fmaf(__uint_as_float((u).y << 16), (d), a2); \
        a3 = fmaf(__uint_as_float((u).y & 0xFFFF0000u), (d), a3); \
        a4 = fmaf(__uint_as_float((u).z << 16), (d), a4); \
        a5 = fmaf(__uint_as_float((u).z & 0xFFFF0000u), (d), a5); \
        a6 = fmaf(__uint_as_float((u).w << 16), (d), a6); \
        a7 = fmaf(__uint_as_float((u).w & 0xFFFF0000u), (d), a7); } while (0)
    for (; k + 16 <= k1; k += 16) {
        unsigned i0 = csr2[k + slot];
        unsigned i1 = csr2[k + 8 + slot];
        float d0 = dinv[i0], d1 = dinv[i1];
        uint4 u = tbl4[(size_t)i0 * 8 + ch8];
        uint4 v = tbl4[(size_t)i1 * 8 + ch8];
        ACC(u, d0); ACC(v, d1);
    }
    if (k + 8 <= k1) {
        unsigned i0 = csr2[k + slot];
        float d0 = dinv[i0];
        uint4 u = tbl4[(size_t)i0 * 8 + ch8];
        ACC(u, d0);
        k += 8;
    }
    if (k < k1) {
        unsigned rem = k1 - k;
        if ((unsigned)slot < rem) {
            unsigned i0 = csr2[k + slot];
            float d0 = dinv[i0];
            uint4 u = tbl4[(size_t)i0 * 8 + ch8];
            ACC(u, d0);
        }
    }
    a0 += __shfl_xor(a0, 8); a0 += __shfl_xor(a0, 16); a0 += __shfl_xor(a0, 32);
    a1 += __shfl_xor(a1, 8); a1 += __shfl_xor(a1, 16); a1 += __shfl_xor(a1, 32);
    a2 += __shfl_xor(a2, 8); a2 += __shfl_xor(a2, 16); a2 += __shfl_xor(a2, 32);
    a3 += __shfl_xor(a3, 8); a3 += __shfl_xor(a3, 16); a3 += __shfl_xor(a3, 32);
    a4 += __shfl_xor(a4, 8); a4 += __shfl_xor(a4, 16); a4 += __shfl_xor(a4, 32);
    a5 += __shfl_xor(a5, 8); a5 += __shfl_xor(a5, 16); a5 += __shfl_xor(a5, 32);
    a6 += __shfl_xor(a6, 8); a6 += __shfl_xor(a6, 16); a6 += __shfl_xor(a6, 32);
    a7 += __shfl_xor(a7, 8); a7 += __shfl_xor(a7, 16); a7 += __shfl_xor(a7, 32);
    if (lane < 8) {
        float dv = dinv[node];
        uint4 s = tbl4[(size_t)node * 8 + ch8];      // self-loop term
        ACC(s, dv);
        float4 b0 = bias4[ch8 * 2], b1 = bias4[ch8 * 2 + 1];
        float4 r0, r1;
        r0.x = a0 * dv + b0.x; r0.y = a1 * dv + b0.y;
        r0.z = a2 * dv + b0.z; r0.w = a3 * dv + b0.w;
        r1.x = a4 * dv + b1.x; r1.y = a5 * dv + b1.y;
        r1.z = a6 * dv + b1.z; r1.w = a7 * dv + b1.w;
        out4[(size_t)node * 16 + ch8 * 2]     = r0;
        out4[(size_t)node * 16 + ch8 * 2 + 1] = r1;
    }
#undef ACC
}

extern "C" void kernel_launch(void* const* d_in, const int* in_sizes, int n_in,
                              void* d_out, int out_size, void* d_ws, size_t ws_size,
                              hipStream_t stream) {
    const float* x  = (const float*)d_in[0];
    const int*   ei = (const int*)d_in[1];
    const float* W  = (const float*)d_in[2];
    const float* b  = (const float*)d_in[3];

    const int N = in_sizes[0] / N_DIM;   // 65536
    const int E = in_sizes[1] / 2;       // 1048576
    const int* src = ei;
    const int* dst = ei + E;

    // Workspace layout (bytes):
    //   cursor  u32[512*16]     @ 0          (32 KB, line-padded)
    //   dinv    f32[N]          @ 32768      (256 KB)
    //   rsdeg   uint2[N]        @ 294912     (512 KB)
    //   packed  u32[512*4096]   @ 819200     (8 MB padded arena)
    //   csr2    u16[512*4096]   @ 9207808    (4 MB padded arena)
    //   g bf16  u16[N*64]       @ 13402112   (8 MB)   total ~21.4 MB
    char* ws = (char*)d_ws;
    unsigned*       cursor = (unsigned*)(ws);
    float*          dinv   = (float*)   (ws + 32768);
    uint2*          rsdeg  = (uint2*)   (ws + 294912);
    unsigned*       packed = (unsigned*)(ws + 819200);
    unsigned short* csr2   = (unsigned short*)(ws + 9207808);
    unsigned short* g2s    = (unsigned short*)(ws + 13402112);
    const uint4*    tbl4   = (const uint4*)(ws + 13402112);

    const int gemm_blocks = N / 64;   // 1024
    k_init <<<1, NBUCK, 0, stream>>>(cursor);
    k_fused<<<SCAT_NB + gemm_blocks, 512, 0, stream>>>(x, W, src, dst, cursor,
                                                       packed, g2s, E);
    k_sort <<<NBUCK, 512, 0, stream>>>(packed, cursor, csr2, rsdeg, dinv);
    k_pull <<<(N + 3) / 4, 256, 0, stream>>>(tbl4, rsdeg, csr2, dinv,
                                             (const float4*)b, (float4*)d_out, N);
}